// Round 1
// 661.606 us; speedup vs baseline: 1.5245x; 1.5245x over previous
//
#include <hip/hip_runtime.h>
#include <hip/hip_bf16.h>

// NeuronConvNet, Round 5: kill the staging VALU tax.
//  - prep_A kernel precomputes shifted-weight MFMA A-fragments (bf16,
//    fragment-major [g][j][lane][8]) once; gconv blocks just short8-copy
//    them into LDS (was: 20 iters of div/mod + scalar W loads per block,
//    and a 16-way bank conflict on every fragment read).
//  - X staging vectorized: float4 / short8 global loads at aligned
//    origin t0-8, written to the odd-origin LDS layout via b16/b32/b64
//    split writes. Was scalar 4B/2B loads with div-by-270 per element.
//  - XS 272->288: B-read bank offsets {n, n+4, n+16, n+20} -> max 2-way
//    (free). s_c stride 264 spreads the epilogue scatter.
// Math identical to Round 4 (same bf16 rounding path) -> absmax unchanged.

#define T_LEN 4096
#define KK    15
#define TW    256            // output t-tile per block (16 tiles)
#define XS    288            // LDS X row stride (shorts); 2*XS % 128 == 64
#define SCP   264            // s_c row stride (shorts)

typedef __attribute__((ext_vector_type(8))) short    short8;
typedef __attribute__((ext_vector_type(4))) short    short4_t;
typedef __attribute__((ext_vector_type(4))) float    f32x4;
typedef __attribute__((ext_vector_type(2))) unsigned uint2_t;

static __device__ __forceinline__ short f2bf(float f) {
    union { __hip_bfloat16 b; short s; } u; u.b = __float2bfloat16(f); return u.s;
}
static __device__ __forceinline__ float bf2f(short s) {
    union { unsigned u; float f; } u; u.u = ((unsigned)(unsigned short)s) << 16; return u.f;
}

#define MODE_F32   0
#define MODE_BF16  1
#define MODE_SPLIT 2

// ---- Aprep layout: per layer, [g][j][lane][8] bf16, A[m=lane&15][kap] ----
// kap = j*32 + (lane>>4)*8 + e ; A[m][ic*16+kp] = W[g*8+(m&7)][ic][kp-(m>>3)]
#define AP_LEAF  0
#define AP_INT0  327680   // + 64*16*320
#define AP_BR    458752   // + 32*16*256
#define AP_INT1  589824
#define AP_INT2  655360
#define AP_INT3  688128
#define AP_INT4  704512
#define AP_TOTAL 712704

__global__ __launch_bounds__(256) void prep_A(
    const float* __restrict__ W0, const float* __restrict__ W1,
    const float* __restrict__ W2, const float* __restrict__ W3,
    const float* __restrict__ W4, const float* __restrict__ W5,
    const float* __restrict__ W6, short* __restrict__ Ap)
{
    const int idx = blockIdx.x * 256 + threadIdx.x;
    if (idx >= AP_TOTAL) return;
    const float* W; int ipg, base;
    if      (idx < AP_INT0) { W = W0; ipg = 20; base = AP_LEAF; }
    else if (idx < AP_BR)   { W = W1; ipg = 16; base = AP_INT0; }
    else if (idx < AP_INT1) { W = W2; ipg = 16; base = AP_BR;   }
    else if (idx < AP_INT2) { W = W3; ipg = 16; base = AP_INT1; }
    else if (idx < AP_INT3) { W = W4; ipg = 16; base = AP_INT2; }
    else if (idx < AP_INT4) { W = W5; ipg = 16; base = AP_INT3; }
    else                    { W = W6; ipg = 16; base = AP_INT4; }
    const int local = idx - base;
    const int e    = local & 7;
    const int fl   = local >> 3;
    const int lane = fl & 63;
    const int fj   = fl >> 6;           // g*NM + j
    int g, j;
    if (ipg == 20) { g = fj / 10; j = fj - g * 10; }
    else           { g = fj >> 3; j = fj & 7; }
    const int m   = lane & 15;
    const int kap = j * 32 + (lane >> 4) * 8 + e;
    const int ic  = kap >> 4, kp = kap & 15;
    const int k   = kp - (m >> 3);
    float v = 0.f;
    if (k >= 0 && k < KK)
        v = W[((size_t)(g * 8 + (m & 7)) * ipg + ic) * KK + k];
    Ap[idx] = f2bf(v);
}

// MODE_F32  : inA fp32, ch = g*IPG + r            (leaf; reads x)
// MODE_BF16 : inA bf16, ch = g*IPG + r            (int layers)
// MODE_SPLIT: r<8 from inA bf16 (ch=g*8+r), r>=8 from inX fp32
template <int IPG, int MODE>
__global__ __launch_bounds__(256) void gconv_mfma(
    const void*  __restrict__ inA_, int cinA,
    const float* __restrict__ inX,  int cinX, int xbase,
    const short* __restrict__ Ap,      // layer base pre-added
    const float* __restrict__ bias,
    short* __restrict__ out, int Cout)
{
    constexpr int KD = IPG * 16;   // padded K dim (320 or 256)
    constexpr int NM = KD / 32;    // MFMAs per output tile (10 or 8)

    __shared__ __align__(16) short s_x[IPG * XS];
    __shared__ __align__(16) short s_a[16 * KD];
    __shared__ __align__(16) short s_c[8 * SCP];

    const int tile = blockIdx.x, g = blockIdx.y, b = blockIdx.z;
    const int tid  = threadIdx.x;
    const int t_base = tile * TW - 8;   // aligned staging origin (LDS p=0 <-> t0-7)

    // ---- A: straight vectorized copy of precomputed fragments ----
    {
        const short* Ag = Ap + (size_t)g * (16 * KD);
        for (int i = tid; i < 2 * KD; i += 256)
            *(short8*)&s_a[i * 8] = *(const short8*)&Ag[i * 8];
    }

    // ---- X staging, vectorized; LDS value p <-> global t0-7+p ----
    if constexpr (MODE == MODE_BF16) {
        for (int v = tid; v < IPG * 34; v += 256) {
            const int r = v / 34, u = v - r * 34;
            const int gtb = t_base + 8 * u;          // multiple of 8: never partial OOB
            short8 sv = {0, 0, 0, 0, 0, 0, 0, 0};
            if (gtb >= 0 && gtb < T_LEN)
                sv = *(const short8*)((const short*)inA_ +
                      ((size_t)b * cinA + g * IPG + r) * T_LEN + gtb);
            short* row = s_x + r * XS;
            const int p0 = 8 * u;                    // element gtb+1 lands at p0
            if (u > 0) row[p0 - 1] = sv[0];
            uint2_t w;
            w.x = (unsigned short)sv[1] | ((unsigned)(unsigned short)sv[2] << 16);
            w.y = (unsigned short)sv[3] | ((unsigned)(unsigned short)sv[4] << 16);
            *(uint2_t*)(row + p0) = w;               // byte 576r+16u: 8B aligned
            *(unsigned*)(row + p0 + 4) =
                (unsigned short)sv[5] | ((unsigned)(unsigned short)sv[6] << 16);
            row[p0 + 6] = sv[7];
        }
    } else {
        for (int v = tid; v < IPG * 68; v += 256) {
            const int r = v / 68, u = v - r * 68;
            const int gtb = t_base + 4 * u;          // multiple of 4: never partial OOB
            short h0 = 0, h1 = 0, h2 = 0, h3 = 0;
            if (gtb >= 0 && gtb < T_LEN) {
                if constexpr (MODE == MODE_F32) {
                    f32x4 f = *(const f32x4*)((const float*)inA_ +
                          ((size_t)b * cinA + g * IPG + r) * T_LEN + gtb);
                    h0 = f2bf(f[0]); h1 = f2bf(f[1]); h2 = f2bf(f[2]); h3 = f2bf(f[3]);
                } else {               // MODE_SPLIT
                    if (r < 8) {
                        short4_t sv = *(const short4_t*)((const short*)inA_ +
                              ((size_t)b * cinA + g * 8 + r) * T_LEN + gtb);
                        h0 = sv[0]; h1 = sv[1]; h2 = sv[2]; h3 = sv[3];
                    } else {
                        f32x4 f = *(const f32x4*)(inX +
                              ((size_t)b * cinX + xbase + g * 8 + (r - 8)) * T_LEN + gtb);
                        h0 = f2bf(f[0]); h1 = f2bf(f[1]); h2 = f2bf(f[2]); h3 = f2bf(f[3]);
                    }
                }
            }
            short* row = s_x + r * XS;
            const int p0 = 4 * u;
            if (u > 0) row[p0 - 1] = h0;
            *(unsigned*)(row + p0) =                 // byte 576r+8u: 4B aligned
                (unsigned short)h1 | ((unsigned)(unsigned short)h2 << 16);
            row[p0 + 2] = h3;
        }
    }
    __syncthreads();

    const int l  = tid & 63;          // lane
    const int wv = tid >> 6;          // wave 0..3 (uniform)
    const int n  = l & 15, q = l >> 4;

    // fragment-major: wave reads 1KB contiguous -> conflict-free b128
    short8 fa[NM];
#pragma unroll
    for (int j = 0; j < NM; ++j)
        fa[j] = *(const short8*)&s_a[(j * 64 + l) * 8];

    float bv[4];
#pragma unroll
    for (int r = 0; r < 4; ++r) bv[r] = bias[g * 8 + ((q * 4 + r) & 7)];

    for (int c = 0; c < 2; ++c) {
        const int co = (wv * 2 + c) * 32;   // chunk t-offset within tile
        f32x4 acc = {bv[0], bv[1], bv[2], bv[3]};
#pragma unroll
        for (int j = 0; j < NM; ++j) {
            const int ic  = j * 2 + (q >> 1);
            const int idx = co + 2 * n + ((q & 1) * 8);    // even -> 4B aligned
            const unsigned* bp = (const unsigned*)&s_x[ic * XS + idx];
            union { unsigned u[4]; short8 v; } bb;
            bb.u[0] = bp[0]; bb.u[1] = bp[1]; bb.u[2] = bp[2]; bb.u[3] = bp[3];
            acc = __builtin_amdgcn_mfma_f32_16x16x32_bf16(fa[j], bb.v, acc, 0, 0, 0);
        }
#pragma unroll
        for (int r = 0; r < 4; ++r) {
            float vv = acc[r];
            vv = vv > 0.f ? vv : 0.01f * vv;
            const int m = q * 4 + r, oc = m & 7, s = m >> 3;
            s_c[oc * SCP + co + 2 * n + s] = f2bf(vv);
        }
    }
    __syncthreads();

    // ---- coalesced bf16 store: 8 rows x 256 cols, 16B per thread ----
    {
        const int oc = tid >> 5, col = (tid & 31) * 8;
        const short8 vvv = *(const short8*)&s_c[oc * SCP + col];
        *(short8*)(out + ((size_t)b * Cout + g * 8 + oc) * T_LEN + tile * TW + col) = vvv;
    }
}

// 1x1 conv over 16 bf16 channels -> fp32 out, vectorized x4
__global__ __launch_bounds__(256) void root_kernel(
    const short* __restrict__ h,
    const float* __restrict__ W,
    const float* __restrict__ bias,
    float* __restrict__ out)
{
    const int idx = blockIdx.x * 256 + threadIdx.x;   // (b*T + t)/4
    const int b  = idx >> 10;
    const int t4 = (idx & 1023) * 4;
    const float bb = bias[0];
    float a0 = bb, a1 = bb, a2 = bb, a3 = bb;
#pragma unroll
    for (int ic = 0; ic < 16; ++ic) {
        const short4_t v = *(const short4_t*)&h[((size_t)b * 16 + ic) * T_LEN + t4];
        const float w = W[ic];
        a0 += w * bf2f(v[0]); a1 += w * bf2f(v[1]);
        a2 += w * bf2f(v[2]); a3 += w * bf2f(v[3]);
    }
    f32x4 o = {a0, a1, a2, a3};
    *(f32x4*)&out[(size_t)idx * 4] = o;
}

extern "C" void kernel_launch(void* const* d_in, const int* in_sizes, int n_in,
                              void* d_out, int out_size, void* d_ws, size_t ws_size,
                              hipStream_t stream)
{
    const float* x      = (const float*)d_in[0];
    const float* W_leaf = (const float*)d_in[1];
    const float* b_leaf = (const float*)d_in[2];
    const float* W_int0 = (const float*)d_in[3];
    const float* b_int0 = (const float*)d_in[4];
    const float* W_br   = (const float*)d_in[5];
    const float* b_br   = (const float*)d_in[6];
    const float* W_int1 = (const float*)d_in[7];
    const float* b_int1 = (const float*)d_in[8];
    const float* W_int2 = (const float*)d_in[9];
    const float* b_int2 = (const float*)d_in[10];
    const float* W_int3 = (const float*)d_in[11];
    const float* b_int3 = (const float*)d_in[12];
    const float* W_int4 = (const float*)d_in[13];
    const float* b_int4 = (const float*)d_in[14];
    const float* W_root = (const float*)d_in[15];
    const float* b_root = (const float*)d_in[16];

    // ws: bufA (67.1MB) | bufB (33.6MB) | Aprep (1.43MB) = 102.1MB total
    short* bufA = (short*)d_ws;
    short* bufB = bufA + (size_t)16 * 512 * 4096;
    short* Ap   = bufB + (size_t)16 * 256 * 4096;

    const int tiles = T_LEN / TW;  // 16
    const dim3 blk(256);

    prep_A<<<dim3(AP_TOTAL / 256), blk, 0, stream>>>(
        W_leaf, W_int0, W_br, W_int1, W_int2, W_int3, W_int4, Ap);

    // leaf: x fp32 (ch=g*20+r) -> bufA (512 ch bf16)
    gconv_mfma<20, MODE_F32><<<dim3(tiles, 64, 16), blk, 0, stream>>>(
        x, 1536, nullptr, 0, 0, Ap + AP_LEAF, b_leaf, bufA, 512);
    // int0: bufA (512) -> bufB (256)
    gconv_mfma<16, MODE_BF16><<<dim3(tiles, 32, 16), blk, 0, stream>>>(
        bufA, 512, nullptr, 0, 0, Ap + AP_INT0, b_int0, bufB, 256);
    // br: [bufB (256) | x ch1280..1535 fp32] -> bufA (256)
    gconv_mfma<16, MODE_SPLIT><<<dim3(tiles, 32, 16), blk, 0, stream>>>(
        bufB, 256, x, 1536, 1280, Ap + AP_BR, b_br, bufA, 256);
    // int1: bufA (256) -> bufB (128)
    gconv_mfma<16, MODE_BF16><<<dim3(tiles, 16, 16), blk, 0, stream>>>(
        bufA, 256, nullptr, 0, 0, Ap + AP_INT1, b_int1, bufB, 128);
    // int2: bufB (128) -> bufA (64)
    gconv_mfma<16, MODE_BF16><<<dim3(tiles, 8, 16), blk, 0, stream>>>(
        bufB, 128, nullptr, 0, 0, Ap + AP_INT2, b_int2, bufA, 64);
    // int3: bufA (64) -> bufB (32)
    gconv_mfma<16, MODE_BF16><<<dim3(tiles, 4, 16), blk, 0, stream>>>(
        bufA, 64, nullptr, 0, 0, Ap + AP_INT3, b_int3, bufB, 32);
    // int4: bufB (32) -> bufA (16)
    gconv_mfma<16, MODE_BF16><<<dim3(tiles, 2, 16), blk, 0, stream>>>(
        bufB, 32, nullptr, 0, 0, Ap + AP_INT4, b_int4, bufA, 16);
    // root: bufA (16 ch bf16) -> d_out fp32
    root_kernel<<<dim3((16 * T_LEN / 4) / 256), blk, 0, stream>>>(
        bufA, W_root, b_root, (float*)d_out);
}